// Round 7
// baseline (5327.301 us; speedup 1.0000x reference)
//
#include <hip/hip_runtime.h>
#include <math.h>

// POSTagEncoder: expert-routed linear -> 1-layer LSTM (i,f,g,o) -> time max-pool.
// S=8192, D=128, E=48. Output [1,128] fp32.
//
// Round-7 scan: 512 threads, 8 waves (2/SIMD). Round-4/5/6 counters proved the
// matrix-pipe occupancy is ~16 cyc per 16x16x32 MFMA per SIMD (507 cyc/step,
// invariant to instruction order) -- a structural floor for 512 gate-rows.
// With 1 wave/SIMD the pipe idled ~64% of the step (epilogue + h->barrier->B
// chain + bubbles exposed). This round: wave w owns dims [16w,16w+16) = one
// 16-row tile per gate x 4 K-chunks = 16 MFMA/wave; 2 waves/SIMD overlap one
// wave's epilogue with the other's MFMAs. Update lane (c<4) owns dim 16w+4q+c
// whose 4 gate pre-acts sit in ITS OWN accG[c] (all 16 C columns equal h) --
// 2-level cndmask select, no LDS exchange. Single raw lgkmcnt-only barrier
// per step; [t][dim][gate] xg layout, distance-4 float4 prefetch (all verified
// in rounds 5-6).

#define SEQ   8192
#define DIM   128
#define NGATE 512
#define NEXP  48

typedef _Float16 v8h  __attribute__((ext_vector_type(8)));
typedef float    v4f  __attribute__((ext_vector_type(4)));

__device__ __forceinline__ float sigm_fast(float x) {
    return __fdividef(1.0f, 1.0f + __expf(-x));   // inf-safe both ends
}
__device__ __forceinline__ float tanh_fast(float x) {
    float e = __expf(2.0f * x);
    return 1.0f - __fdividef(2.0f, e + 1.0f);     // +-1 at saturation
}
__device__ __forceinline__ v8h pack8(float4 a, float4 b) {   // RNE converts
    v8h r;
    r[0]=(_Float16)a.x; r[1]=(_Float16)a.y; r[2]=(_Float16)a.z; r[3]=(_Float16)a.w;
    r[4]=(_Float16)b.x; r[5]=(_Float16)b.y; r[6]=(_Float16)b.z; r[7]=(_Float16)b.w;
    return r;
}
// pick component (c&3) of a v4f (2-level cndmask tree)
__device__ __forceinline__ float sel4(v4f A, int c) {
    float v01 = (c & 1) ? A[1] : A[0];
    float v23 = (c & 1) ? A[3] : A[2];
    return (c & 2) ? v23 : v01;
}

// ---------------------------------------------------------------------------
// K1a: z[s] = W_exp[pos_ids[s]] @ embs[s] + b_exp  -> xg[s*512 + 0..128)
// ---------------------------------------------------------------------------
__global__ __launch_bounds__(64) void expert_gemv(
    const float* __restrict__ embs, const int* __restrict__ pos_ids,
    const float* __restrict__ W_exp, const float* __restrict__ b_exp,
    float* __restrict__ xg)
{
    __shared__ float Wl[DIM * DIM];          // 64KB, rows XOR-swizzled
    const int e     = blockIdx.x % NEXP;
    const int slice = blockIdx.x / NEXP;     // 0..7
    const int tid   = threadIdx.x;           // 0..63

    const float4* Wg = (const float4*)(W_exp + (size_t)e * DIM * DIM);
    #pragma unroll 4
    for (int it = 0; it < 64; ++it) {
        int idx = it * 64 + tid;             // 0..4095 float4s
        int r = idx >> 5, c4 = idx & 31;
        float4 v = Wg[idx];
        *(float4*)&Wl[r * DIM + (((c4 ^ (r & 31))) << 2)] = v;
    }
    const float b0 = b_exp[e * DIM + tid];
    const float b1 = b_exp[e * DIM + 64 + tid];
    __syncthreads();

    const int r0 = tid, r1 = tid + 64;
    const int sw0 = r0 & 31, sw1 = r1 & 31;
    const int sBeg = slice * 1024, sEnd = sBeg + 1024;
    for (int base = sBeg; base < sEnd; base += 64) {
        int pid = pos_ids[base + tid];
        unsigned long long m = __ballot(pid == e);
        while (m) {
            int t = __builtin_ctzll(m);
            m &= m - 1;
            int s = base + t;
            const float4* ev = (const float4*)(embs + (size_t)s * DIM);
            float a0 = b0, a1 = b1;
            #pragma unroll
            for (int j4 = 0; j4 < 32; ++j4) {
                float4 x  = ev[j4];
                float4 w0 = *(const float4*)&Wl[r0 * DIM + ((j4 ^ sw0) << 2)];
                float4 w1 = *(const float4*)&Wl[r1 * DIM + ((j4 ^ sw1) << 2)];
                a0 = fmaf(w0.x,x.x,fmaf(w0.y,x.y,fmaf(w0.z,x.z,fmaf(w0.w,x.w,a0))));
                a1 = fmaf(w1.x,x.x,fmaf(w1.y,x.y,fmaf(w1.z,x.z,fmaf(w1.w,x.w,a1))));
            }
            float* zp = xg + (size_t)s * NGATE;
            zp[tid]      = a0;
            zp[tid + 64] = a1;
        }
    }
}

// ---------------------------------------------------------------------------
// K1b: gates = W_ih @ z + b_ih + b_hh, stored PERMUTED: xg[s][dim*4 + gate]
// ---------------------------------------------------------------------------
__global__ __launch_bounds__(256) void gate_gemm(
    const float* __restrict__ W_ih, const float* __restrict__ b_ih,
    const float* __restrict__ b_hh, float* __restrict__ xg)
{
    __shared__ float zl[32 * DIM];    // 16KB
    __shared__ float Wl[64 * DIM];    // 32KB
    const int tid = threadIdx.x;
    const int s0  = blockIdx.x * 32;

    #pragma unroll
    for (int it = 0; it < 4; ++it) {
        int idx = it * 256 + tid;
        int tok = idx >> 5, c4 = idx & 31;
        float4 v = *(const float4*)(xg + ((size_t)(s0 + tok)) * NGATE + (c4 << 2));
        *(float4*)&zl[tok * DIM + (((c4 ^ (tok & 31))) << 2)] = v;
    }
    __syncthreads();

    const int lane = tid & 63;
    const int tg   = tid >> 6;
    const int swr  = lane & 31;

    for (int ch = 0; ch < 8; ++ch) {
        #pragma unroll
        for (int it = 0; it < 8; ++it) {
            int idx = it * 256 + tid;
            int r = idx >> 5, c4 = idx & 31;
            float4 v = *(const float4*)(W_ih + ((size_t)(ch * 64 + r)) * DIM + (c4 << 2));
            *(float4*)&Wl[r * DIM + ((c4 ^ (r & 31)) << 2)] = v;
        }
        __syncthreads();

        const int row = ch * 64 + lane;      // 0..511
        const float bias = b_ih[row] + b_hh[row];
        float acc[8];
        #pragma unroll
        for (int k = 0; k < 8; ++k) acc[k] = bias;
        #pragma unroll 8
        for (int j4 = 0; j4 < 32; ++j4) {
            float4 w = *(const float4*)&Wl[lane * DIM + ((j4 ^ swr) << 2)];
            #pragma unroll
            for (int k = 0; k < 8; ++k) {
                int tok = tg * 8 + k;
                float4 z = *(const float4*)&zl[tok * DIM + ((j4 ^ (tok & 31)) << 2)];
                acc[k] = fmaf(w.x,z.x,fmaf(w.y,z.y,fmaf(w.z,z.z,fmaf(w.w,z.w,acc[k]))));
            }
        }
        const int pidx = ((row & 127) << 2) + (row >> 7);   // dim*4 + gate
        #pragma unroll
        for (int k = 0; k < 8; ++k) {
            int tok = tg * 8 + k;
            xg[((size_t)(s0 + tok)) * NGATE + pidx] = acc[k];
        }
        __syncthreads();
    }
}

// ---------------------------------------------------------------------------
// K2: MFMA LSTM scan + max-pool. ONE block, 512 threads (8 waves, 2/SIMD).
// Wave w owns dims [16w,16w+16): one 16-row tile per gate, K=128 in 4 chunks
// of mfma_f32_16x16x32_f16 (16 MFMA/wave/step). B columns all = h (fp16 LDS,
// double-buffered). Update lane (q,c<4) owns dim 16w+4q+c; its 4 gate pre-acts
// are accG[c] in its own registers (all C columns equal).
// ---------------------------------------------------------------------------
__global__ __launch_bounds__(512, 2) void lstm_scan(
    const float* __restrict__ xg, const float* __restrict__ W_hh,
    float* __restrict__ out)
{
    const int T    = threadIdx.x;    // 0..511
    const int w    = T >> 6;         // wave id: owns dims [16w, 16w+16)
    const int lane = T & 63;
    const int q    = lane >> 4;      // quad 0..3
    const int c    = lane & 15;      // A row-in-tile; C column
    const int q8   = q * 8;
    const bool upd = (c < 4);        // 16 update lanes per wave
    const int d    = w * 16 + q * 4 + c;     // valid when upd

    __shared__ __align__(16) _Float16 hbuf[2][DIM];

    // ---- A-fragments: gate G tile rows = G*128 + w*16 + c, 4 K-chunks;
    //      named vars, MFMA-only use -> AGPR-resident (64 regs total) ----
#define LOADA(G) \
    v8h a##G##_0, a##G##_1, a##G##_2, a##G##_3; { \
        const float4* p = (const float4*)(W_hh + \
            (size_t)((G) * 128 + w * 16 + c) * DIM) + q * 2; \
        a##G##_0 = pack8(p[ 0], p[ 1]); \
        a##G##_1 = pack8(p[ 8], p[ 9]); \
        a##G##_2 = pack8(p[16], p[17]); \
        a##G##_3 = pack8(p[24], p[25]); }
    LOADA(0) LOADA(1) LOADA(2) LOADA(3)
#undef LOADA

    float cst  = 0.0f;
    float hmax = -INFINITY;

    if (upd) hbuf[0][d] = (_Float16)0.0f;    // h_0 = 0
    __syncthreads();                          // once; vmcnt drain harmless here

    // xg prefetch pipeline, distance 4 (raw barriers keep these in flight)
    float4 X0 = {0,0,0,0}, X1 = X0, X2 = X0, X3 = X0;
    if (upd) {
        X0 = *(const float4*)(xg + (size_t)0 * NGATE + 4 * d);
        X1 = *(const float4*)(xg + (size_t)1 * NGATE + 4 * d);
        X2 = *(const float4*)(xg + (size_t)2 * NGATE + 4 * d);
        X3 = *(const float4*)(xg + (size_t)3 * NGATE + 4 * d);
    }

    const v4f Z4 = {0.0f, 0.0f, 0.0f, 0.0f};

#define MF(G,K,B,CIN) __builtin_amdgcn_mfma_f32_16x16x32_f16(a##G##_##K, B, CIN, 0, 0, 0)

#define STEP(XV, tp, bf, nbf) { \
    const v8h B0 = *(const v8h*)&hbuf[bf][ 0 + q8]; \
    const v8h B1 = *(const v8h*)&hbuf[bf][32 + q8]; \
    const v8h B2 = *(const v8h*)&hbuf[bf][64 + q8]; \
    const v8h B3 = *(const v8h*)&hbuf[bf][96 + q8]; \
    float4 xcur = XV; \
    if (upd) XV = *(const float4*)(xg + (size_t)(tp) * NGATE + 4 * d); \
    /* K-major: 4 independent MFMAs (one per gate) between accumulator reuses */ \
    v4f c0 = MF(0,0,B0,Z4);  v4f c1 = MF(1,0,B0,Z4); \
    v4f c2 = MF(2,0,B0,Z4);  v4f c3 = MF(3,0,B0,Z4); \
    c0 = MF(0,1,B1,c0);  c1 = MF(1,1,B1,c1);  c2 = MF(2,1,B1,c2);  c3 = MF(3,1,B1,c3); \
    c0 = MF(0,2,B2,c0);  c1 = MF(1,2,B2,c1);  c2 = MF(2,2,B2,c2);  c3 = MF(3,2,B2,c3); \
    c0 = MF(0,3,B3,c0);  c1 = MF(1,3,B3,c1);  c2 = MF(2,3,B3,c2);  c3 = MF(3,3,B3,c3); \
    if (upd) { \
        const float pi = sel4(c0, c) + xcur.x; \
        const float pf = sel4(c1, c) + xcur.y; \
        const float pg = sel4(c2, c) + xcur.z; \
        const float po = sel4(c3, c) + xcur.w; \
        const float iv = sigm_fast(pi); \
        const float fv = sigm_fast(pf); \
        const float gv = tanh_fast(pg); \
        const float ov = sigm_fast(po); \
        cst = fmaf(fv, cst, iv * gv); \
        const float h = ov * tanh_fast(cst); \
        hmax = fmaxf(hmax, h); \
        hbuf[nbf][d] = (_Float16)h; \
    } \
    asm volatile("s_waitcnt lgkmcnt(0)\n\ts_barrier" ::: "memory"); }

    for (int t = 0; t < SEQ; t += 4) {
        const int t4 = (t + 4 < SEQ) ? t + 4 : SEQ - 1;
        const int t5 = (t + 5 < SEQ) ? t + 5 : SEQ - 1;
        const int t6 = (t + 6 < SEQ) ? t + 6 : SEQ - 1;
        const int t7 = (t + 7 < SEQ) ? t + 7 : SEQ - 1;
        STEP(X0, t4, 0, 1)
        STEP(X1, t5, 1, 0)
        STEP(X2, t6, 0, 1)
        STEP(X3, t7, 1, 0)
    }
#undef STEP
#undef MF

    if (upd) out[d] = hmax;   // out[1][128]
}

// ---------------------------------------------------------------------------
extern "C" void kernel_launch(void* const* d_in, const int* in_sizes, int n_in,
                              void* d_out, int out_size, void* d_ws, size_t ws_size,
                              hipStream_t stream)
{
    const float* embs  = (const float*)d_in[0];
    const int*   pos   = (const int*)  d_in[1];
    const float* W_exp = (const float*)d_in[2];
    const float* b_exp = (const float*)d_in[3];
    const float* W_ih  = (const float*)d_in[4];
    const float* W_hh  = (const float*)d_in[5];
    const float* b_ih  = (const float*)d_in[6];
    const float* b_hh  = (const float*)d_in[7];
    float* out = (float*)d_out;
    float* xg  = (float*)d_ws;   // [SEQ][512] fp32 = 16 MB

    expert_gemv<<<dim3(NEXP * 8), 64, 0, stream>>>(embs, pos, W_exp, b_exp, xg);
    gate_gemm  <<<dim3(256), 256, 0, stream>>>(W_ih, b_ih, b_hh, xg);
    lstm_scan  <<<dim3(1), 512, 0, stream>>>(xg, W_hh, out);
}

// Round 8
// 4884.118 us; speedup vs baseline: 1.0907x; 1.0907x over previous
//
#include <hip/hip_runtime.h>
#include <math.h>

// POSTagEncoder: expert-routed linear -> 1-layer LSTM (i,f,g,o) -> time max-pool.
// S=8192, D=128, E=48. Output [1,128] fp32.
//
// Round-8 scan: round-6 config (4 waves, 1/SIMD -- beat 8 waves: LDS B-read
// traffic and barrier cost scale with waves while the 512-cyc matrix wall is
// invariant), with the ~630 cyc/step of measured slack attacked:
//   - NO exec-mask churn in the loop: all 64 lanes run the epilogue (lanes
//     c>=8 mirror c-8; duplicate same-value ds_write_b16 is benign, 2-way free),
//     xg prefetch unconditional -> clean vmcnt pipelining.
//   - fixed per-lane xg column pointer, unroll-2 (hbuf parity), distance-2
//     prefetch (1 step ~585ns >> L2/L3 latency).
// Kept (all counter-verified rounds 5-7): raw lgkmcnt-only barrier (1/step),
// K-major MFMA order, per-wave dim ownership with in-register gate select,
// [t][dim][gate] xg layout, A-fragments as named v8h vars (AGPR-resident).

#define SEQ   8192
#define DIM   128
#define NGATE 512
#define NEXP  48

typedef _Float16 v8h  __attribute__((ext_vector_type(8)));
typedef float    v4f  __attribute__((ext_vector_type(4)));

__device__ __forceinline__ float sigm_fast(float x) {
    return __fdividef(1.0f, 1.0f + __expf(-x));   // inf-safe both ends
}
__device__ __forceinline__ float tanh_fast(float x) {
    float e = __expf(2.0f * x);
    return 1.0f - __fdividef(2.0f, e + 1.0f);     // +-1 at saturation
}
__device__ __forceinline__ v8h pack8(float4 a, float4 b) {   // RNE converts
    v8h r;
    r[0]=(_Float16)a.x; r[1]=(_Float16)a.y; r[2]=(_Float16)a.z; r[3]=(_Float16)a.w;
    r[4]=(_Float16)b.x; r[5]=(_Float16)b.y; r[6]=(_Float16)b.z; r[7]=(_Float16)b.w;
    return r;
}
// select component (c&1,c&2) from A (half 0) or B (half 1) per (c&4)
__device__ __forceinline__ float selv(v4f A, v4f B, int c) {
    float a01 = (c & 1) ? A[1] : A[0];
    float a23 = (c & 1) ? A[3] : A[2];
    float av  = (c & 2) ? a23 : a01;
    float b01 = (c & 1) ? B[1] : B[0];
    float b23 = (c & 1) ? B[3] : B[2];
    float bv  = (c & 2) ? b23 : b01;
    return (c & 4) ? bv : av;
}

// ---------------------------------------------------------------------------
// K1a: z[s] = W_exp[pos_ids[s]] @ embs[s] + b_exp  -> xg[s*512 + 0..128)
// ---------------------------------------------------------------------------
__global__ __launch_bounds__(64) void expert_gemv(
    const float* __restrict__ embs, const int* __restrict__ pos_ids,
    const float* __restrict__ W_exp, const float* __restrict__ b_exp,
    float* __restrict__ xg)
{
    __shared__ float Wl[DIM * DIM];          // 64KB, rows XOR-swizzled
    const int e     = blockIdx.x % NEXP;
    const int slice = blockIdx.x / NEXP;     // 0..7
    const int tid   = threadIdx.x;           // 0..63

    const float4* Wg = (const float4*)(W_exp + (size_t)e * DIM * DIM);
    #pragma unroll 4
    for (int it = 0; it < 64; ++it) {
        int idx = it * 64 + tid;             // 0..4095 float4s
        int r = idx >> 5, c4 = idx & 31;
        float4 v = Wg[idx];
        *(float4*)&Wl[r * DIM + (((c4 ^ (r & 31))) << 2)] = v;
    }
    const float b0 = b_exp[e * DIM + tid];
    const float b1 = b_exp[e * DIM + 64 + tid];
    __syncthreads();

    const int r0 = tid, r1 = tid + 64;
    const int sw0 = r0 & 31, sw1 = r1 & 31;
    const int sBeg = slice * 1024, sEnd = sBeg + 1024;
    for (int base = sBeg; base < sEnd; base += 64) {
        int pid = pos_ids[base + tid];
        unsigned long long m = __ballot(pid == e);
        while (m) {
            int t = __builtin_ctzll(m);
            m &= m - 1;
            int s = base + t;
            const float4* ev = (const float4*)(embs + (size_t)s * DIM);
            float a0 = b0, a1 = b1;
            #pragma unroll
            for (int j4 = 0; j4 < 32; ++j4) {
                float4 x  = ev[j4];
                float4 w0 = *(const float4*)&Wl[r0 * DIM + ((j4 ^ sw0) << 2)];
                float4 w1 = *(const float4*)&Wl[r1 * DIM + ((j4 ^ sw1) << 2)];
                a0 = fmaf(w0.x,x.x,fmaf(w0.y,x.y,fmaf(w0.z,x.z,fmaf(w0.w,x.w,a0))));
                a1 = fmaf(w1.x,x.x,fmaf(w1.y,x.y,fmaf(w1.z,x.z,fmaf(w1.w,x.w,a1))));
            }
            float* zp = xg + (size_t)s * NGATE;
            zp[tid]      = a0;
            zp[tid + 64] = a1;
        }
    }
}

// ---------------------------------------------------------------------------
// K1b: gates = W_ih @ z + b_ih + b_hh, stored PERMUTED: xg[s][dim*4 + gate]
// ---------------------------------------------------------------------------
__global__ __launch_bounds__(256) void gate_gemm(
    const float* __restrict__ W_ih, const float* __restrict__ b_ih,
    const float* __restrict__ b_hh, float* __restrict__ xg)
{
    __shared__ float zl[32 * DIM];    // 16KB
    __shared__ float Wl[64 * DIM];    // 32KB
    const int tid = threadIdx.x;
    const int s0  = blockIdx.x * 32;

    #pragma unroll
    for (int it = 0; it < 4; ++it) {
        int idx = it * 256 + tid;
        int tok = idx >> 5, c4 = idx & 31;
        float4 v = *(const float4*)(xg + ((size_t)(s0 + tok)) * NGATE + (c4 << 2));
        *(float4*)&zl[tok * DIM + (((c4 ^ (tok & 31))) << 2)] = v;
    }
    __syncthreads();

    const int lane = tid & 63;
    const int tg   = tid >> 6;
    const int swr  = lane & 31;

    for (int ch = 0; ch < 8; ++ch) {
        #pragma unroll
        for (int it = 0; it < 8; ++it) {
            int idx = it * 256 + tid;
            int r = idx >> 5, c4 = idx & 31;
            float4 v = *(const float4*)(W_ih + ((size_t)(ch * 64 + r)) * DIM + (c4 << 2));
            *(float4*)&Wl[r * DIM + ((c4 ^ (r & 31)) << 2)] = v;
        }
        __syncthreads();

        const int row = ch * 64 + lane;      // 0..511
        const float bias = b_ih[row] + b_hh[row];
        float acc[8];
        #pragma unroll
        for (int k = 0; k < 8; ++k) acc[k] = bias;
        #pragma unroll 8
        for (int j4 = 0; j4 < 32; ++j4) {
            float4 w = *(const float4*)&Wl[lane * DIM + ((j4 ^ swr) << 2)];
            #pragma unroll
            for (int k = 0; k < 8; ++k) {
                int tok = tg * 8 + k;
                float4 z = *(const float4*)&zl[tok * DIM + ((j4 ^ (tok & 31)) << 2)];
                acc[k] = fmaf(w.x,z.x,fmaf(w.y,z.y,fmaf(w.z,z.z,fmaf(w.w,z.w,acc[k]))));
            }
        }
        const int pidx = ((row & 127) << 2) + (row >> 7);   // dim*4 + gate
        #pragma unroll
        for (int k = 0; k < 8; ++k) {
            int tok = tg * 8 + k;
            xg[((size_t)(s0 + tok)) * NGATE + pidx] = acc[k];
        }
        __syncthreads();
    }
}

// ---------------------------------------------------------------------------
// K2: MFMA LSTM scan + max-pool. ONE block, 256 threads (4 waves, 1/SIMD).
// Wave wg owns dims [32wg,32wg+32): 8 tiles (gate x half) of 16 rows, K=128 in
// 4 chunks of mfma_f32_16x16x32_f16, K-major issue. Branch-free loop body.
// ---------------------------------------------------------------------------
__global__ __launch_bounds__(256, 1) void lstm_scan(
    const float* __restrict__ xg, const float* __restrict__ W_hh,
    float* __restrict__ out)
{
    const int T    = threadIdx.x;
    const int wg   = T >> 6;         // wave id: owns dims [32*wg, 32*wg+32)
    const int lane = T & 63;
    const int q    = lane >> 4;      // quad 0..3
    const int c    = lane & 15;      // A row-in-tile; C column
    const int q8   = q * 8;
    // dim owned by this lane's epilogue; lanes c>=8 mirror c-8 (same d, same
    // values -> duplicate identical LDS writes, benign)
    const int d    = wg * 32 + q * 4 + (c & 3) + ((c & 4) ? 16 : 0);

    __shared__ __align__(16) _Float16 hbuf[2][DIM];

    // ---- A-fragments: tile (gate G, half H) rows = G*128 + wg*32 + H*16 + c,
    //      4 K-chunks each; named vars, MFMA-only use -> AGPR-resident ----
#define LOADA(G,H) \
    v8h a##G##H##0, a##G##H##1, a##G##H##2, a##G##H##3; { \
        const float4* p = (const float4*)(W_hh + \
            (size_t)((G) * 128 + wg * 32 + (H) * 16 + c) * DIM) + q * 2; \
        a##G##H##0 = pack8(p[ 0], p[ 1]); \
        a##G##H##1 = pack8(p[ 8], p[ 9]); \
        a##G##H##2 = pack8(p[16], p[17]); \
        a##G##H##3 = pack8(p[24], p[25]); }
    LOADA(0,0) LOADA(0,1) LOADA(1,0) LOADA(1,1)
    LOADA(2,0) LOADA(2,1) LOADA(3,0) LOADA(3,1)
#undef LOADA

    float cst  = 0.0f;
    float hmax = -INFINITY;

    if (T < DIM) hbuf[0][T] = (_Float16)0.0f;   // h_0 = 0
    __syncthreads();                             // once; vmcnt drain harmless

    // per-lane xg column pointer ([t][dim][gate] layout), distance-2 prefetch
    const float* xp = xg + 4 * d;
    float4 X0 = *(const float4*)(xp);            // t = 0
    float4 X1 = *(const float4*)(xp + NGATE);    // t = 1

    const v4f Z4 = {0.0f, 0.0f, 0.0f, 0.0f};

#define MF(G,H,K,B,CIN) __builtin_amdgcn_mfma_f32_16x16x32_f16(a##G##H##K, B, CIN, 0, 0, 0)

#define STEP(XV, tp, bf, nbf) { \
    const v8h B0 = *(const v8h*)&hbuf[bf][ 0 + q8]; \
    const v8h B1 = *(const v8h*)&hbuf[bf][32 + q8]; \
    const v8h B2 = *(const v8h*)&hbuf[bf][64 + q8]; \
    const v8h B3 = *(const v8h*)&hbuf[bf][96 + q8]; \
    const float4 xcur = XV; \
    XV = *(const float4*)(xp + (size_t)(tp) * NGATE); \
    /* K-major: 8 independent MFMAs between accumulator reuses */ \
    v4f c00 = MF(0,0,0,B0,Z4);  v4f c01 = MF(0,1,0,B0,Z4); \
    v4f c10 = MF(1,0,0,B0,Z4);  v4f c11 = MF(1,1,0,B0,Z4); \
    v4f c20 = MF(2,0,0,B0,Z4);  v4f c21 = MF(2,1,0,B0,Z4); \
    v4f c30 = MF(3,0,0,B0,Z4);  v4f c31 = MF(3,1,0,B0,Z4); \
    c00 = MF(0,0,1,B1,c00);  c01 = MF(0,1,1,B1,c01); \
    c10 = MF(1,0,1,B1,c10);  c11 = MF(1,1,1,B1,c11); \
    c20 = MF(2,0,1,B1,c20);  c21 = MF(2,1,1,B1,c21); \
    c30 = MF(3,0,1,B1,c30);  c31 = MF(3,1,1,B1,c31); \
    c00 = MF(0,0,2,B2,c00);  c01 = MF(0,1,2,B2,c01); \
    c10 = MF(1,0,2,B2,c10);  c11 = MF(1,1,2,B2,c11); \
    c20 = MF(2,0,2,B2,c20);  c21 = MF(2,1,2,B2,c21); \
    c30 = MF(3,0,2,B2,c30);  c31 = MF(3,1,2,B2,c31); \
    c00 = MF(0,0,3,B3,c00);  c01 = MF(0,1,3,B3,c01); \
    c10 = MF(1,0,3,B3,c10);  c11 = MF(1,1,3,B3,c11); \
    c20 = MF(2,0,3,B3,c20);  c21 = MF(2,1,3,B3,c21); \
    c30 = MF(3,0,3,B3,c30);  c31 = MF(3,1,3,B3,c31); \
    /* branch-free epilogue on ALL lanes (c>=8 mirrors c-8) */ \
    const float pi = selv(c00, c01, c) + xcur.x; \
    const float pf = selv(c10, c11, c) + xcur.y; \
    const float pg = selv(c20, c21, c) + xcur.z; \
    const float po = selv(c30, c31, c) + xcur.w; \
    const float iv = sigm_fast(pi); \
    const float fv = sigm_fast(pf); \
    const float gv = tanh_fast(pg); \
    const float ov = sigm_fast(po); \
    cst = fmaf(fv, cst, iv * gv); \
    const float h = ov * tanh_fast(cst); \
    hmax = fmaxf(hmax, h); \
    hbuf[nbf][d] = (_Float16)h; \
    asm volatile("s_waitcnt lgkmcnt(0)\n\ts_barrier" ::: "memory"); }

    for (int t = 0; t < SEQ; t += 2) {
        const int tp0 = (t + 2 < SEQ) ? t + 2 : SEQ - 1;
        const int tp1 = (t + 3 < SEQ) ? t + 3 : SEQ - 1;
        STEP(X0, tp0, 0, 1)
        STEP(X1, tp1, 1, 0)
    }
#undef STEP
#undef MF

    if (c < 8) out[d] = hmax;   // 32 unique dims per wave -> out[1][128]
}

// ---------------------------------------------------------------------------
extern "C" void kernel_launch(void* const* d_in, const int* in_sizes, int n_in,
                              void* d_out, int out_size, void* d_ws, size_t ws_size,
                              hipStream_t stream)
{
    const float* embs  = (const float*)d_in[0];
    const int*   pos   = (const int*)  d_in[1];
    const float* W_exp = (const float*)d_in[2];
    const float* b_exp = (const float*)d_in[3];
    const float* W_ih  = (const float*)d_in[4];
    const float* W_hh  = (const float*)d_in[5];
    const float* b_ih  = (const float*)d_in[6];
    const float* b_hh  = (const float*)d_in[7];
    float* out = (float*)d_out;
    float* xg  = (float*)d_ws;   // [SEQ][512] fp32 = 16 MB

    expert_gemv<<<dim3(NEXP * 8), 64, 0, stream>>>(embs, pos, W_exp, b_exp, xg);
    gate_gemm  <<<dim3(256), 256, 0, stream>>>(W_ih, b_ih, b_hh, xg);
    lstm_scan  <<<dim3(1), 256, 0, stream>>>(xg, W_hh, out);
}

// Round 9
// 4831.245 us; speedup vs baseline: 1.1027x; 1.0109x over previous
//
#include <hip/hip_runtime.h>
#include <math.h>

// POSTagEncoder: expert-routed linear -> 1-layer LSTM (i,f,g,o) -> time max-pool.
// S=8192, D=128, E=48. Output [1,128] fp32.
//
// Round-9 scan change (single variable): xg prefetch via INLINE-ASM loads with
// manual vmcnt control. Rounds 4-8 localized a ~600-cyc/step serial-latency
// residual; the only uncontrolled mechanism left is compiler waitcnt placement
// on the xg loads (per m131/m141 the compiler defeats source-level vmcnt
// pipelining). Asm loads are invisible to SIInsertWaitcnts -> no compiler
// vmcnt in the loop; we keep 8 loads in flight and wait vmcnt(7) per step
// (issue-ordered counter => exactly row-t's load completes). __syncthreads
// after the weight prologue zeroes the HW counter so the invariant is exact.
// Everything else identical to round 8 (4 waves 1/SIMD, K-major MFMA, raw
// lgkmcnt-only barrier, branch-free epilogue, [t][dim][gate] xg layout).

#define SEQ   8192
#define DIM   128
#define NGATE 512
#define NEXP  48

typedef _Float16 v8h  __attribute__((ext_vector_type(8)));
typedef float    v4f  __attribute__((ext_vector_type(4)));

__device__ __forceinline__ float sigm_fast(float x) {
    return __fdividef(1.0f, 1.0f + __expf(-x));   // inf-safe both ends
}
__device__ __forceinline__ float tanh_fast(float x) {
    float e = __expf(2.0f * x);
    return 1.0f - __fdividef(2.0f, e + 1.0f);     // +-1 at saturation
}
__device__ __forceinline__ v8h pack8(float4 a, float4 b) {   // RNE converts
    v8h r;
    r[0]=(_Float16)a.x; r[1]=(_Float16)a.y; r[2]=(_Float16)a.z; r[3]=(_Float16)a.w;
    r[4]=(_Float16)b.x; r[5]=(_Float16)b.y; r[6]=(_Float16)b.z; r[7]=(_Float16)b.w;
    return r;
}
// select component (c&1,c&2) from A (half 0) or B (half 1) per (c&4)
__device__ __forceinline__ float selv(v4f A, v4f B, int c) {
    float a01 = (c & 1) ? A[1] : A[0];
    float a23 = (c & 1) ? A[3] : A[2];
    float av  = (c & 2) ? a23 : a01;
    float b01 = (c & 1) ? B[1] : B[0];
    float b23 = (c & 1) ? B[3] : B[2];
    float bv  = (c & 2) ? b23 : b01;
    return (c & 4) ? bv : av;
}

// ---------------------------------------------------------------------------
// K1a: z[s] = W_exp[pos_ids[s]] @ embs[s] + b_exp  -> xg[s*512 + 0..128)
// ---------------------------------------------------------------------------
__global__ __launch_bounds__(64) void expert_gemv(
    const float* __restrict__ embs, const int* __restrict__ pos_ids,
    const float* __restrict__ W_exp, const float* __restrict__ b_exp,
    float* __restrict__ xg)
{
    __shared__ float Wl[DIM * DIM];          // 64KB, rows XOR-swizzled
    const int e     = blockIdx.x % NEXP;
    const int slice = blockIdx.x / NEXP;     // 0..7
    const int tid   = threadIdx.x;           // 0..63

    const float4* Wg = (const float4*)(W_exp + (size_t)e * DIM * DIM);
    #pragma unroll 4
    for (int it = 0; it < 64; ++it) {
        int idx = it * 64 + tid;             // 0..4095 float4s
        int r = idx >> 5, c4 = idx & 31;
        float4 v = Wg[idx];
        *(float4*)&Wl[r * DIM + (((c4 ^ (r & 31))) << 2)] = v;
    }
    const float b0 = b_exp[e * DIM + tid];
    const float b1 = b_exp[e * DIM + 64 + tid];
    __syncthreads();

    const int r0 = tid, r1 = tid + 64;
    const int sw0 = r0 & 31, sw1 = r1 & 31;
    const int sBeg = slice * 1024, sEnd = sBeg + 1024;
    for (int base = sBeg; base < sEnd; base += 64) {
        int pid = pos_ids[base + tid];
        unsigned long long m = __ballot(pid == e);
        while (m) {
            int t = __builtin_ctzll(m);
            m &= m - 1;
            int s = base + t;
            const float4* ev = (const float4*)(embs + (size_t)s * DIM);
            float a0 = b0, a1 = b1;
            #pragma unroll
            for (int j4 = 0; j4 < 32; ++j4) {
                float4 x  = ev[j4];
                float4 w0 = *(const float4*)&Wl[r0 * DIM + ((j4 ^ sw0) << 2)];
                float4 w1 = *(const float4*)&Wl[r1 * DIM + ((j4 ^ sw1) << 2)];
                a0 = fmaf(w0.x,x.x,fmaf(w0.y,x.y,fmaf(w0.z,x.z,fmaf(w0.w,x.w,a0))));
                a1 = fmaf(w1.x,x.x,fmaf(w1.y,x.y,fmaf(w1.z,x.z,fmaf(w1.w,x.w,a1))));
            }
            float* zp = xg + (size_t)s * NGATE;
            zp[tid]      = a0;
            zp[tid + 64] = a1;
        }
    }
}

// ---------------------------------------------------------------------------
// K1b: gates = W_ih @ z + b_ih + b_hh, stored PERMUTED: xg[s][dim*4 + gate]
// ---------------------------------------------------------------------------
__global__ __launch_bounds__(256) void gate_gemm(
    const float* __restrict__ W_ih, const float* __restrict__ b_ih,
    const float* __restrict__ b_hh, float* __restrict__ xg)
{
    __shared__ float zl[32 * DIM];    // 16KB
    __shared__ float Wl[64 * DIM];    // 32KB
    const int tid = threadIdx.x;
    const int s0  = blockIdx.x * 32;

    #pragma unroll
    for (int it = 0; it < 4; ++it) {
        int idx = it * 256 + tid;
        int tok = idx >> 5, c4 = idx & 31;
        float4 v = *(const float4*)(xg + ((size_t)(s0 + tok)) * NGATE + (c4 << 2));
        *(float4*)&zl[tok * DIM + (((c4 ^ (tok & 31))) << 2)] = v;
    }
    __syncthreads();

    const int lane = tid & 63;
    const int tg   = tid >> 6;
    const int swr  = lane & 31;

    for (int ch = 0; ch < 8; ++ch) {
        #pragma unroll
        for (int it = 0; it < 8; ++it) {
            int idx = it * 256 + tid;
            int r = idx >> 5, c4 = idx & 31;
            float4 v = *(const float4*)(W_ih + ((size_t)(ch * 64 + r)) * DIM + (c4 << 2));
            *(float4*)&Wl[r * DIM + ((c4 ^ (r & 31)) << 2)] = v;
        }
        __syncthreads();

        const int row = ch * 64 + lane;      // 0..511
        const float bias = b_ih[row] + b_hh[row];
        float acc[8];
        #pragma unroll
        for (int k = 0; k < 8; ++k) acc[k] = bias;
        #pragma unroll 8
        for (int j4 = 0; j4 < 32; ++j4) {
            float4 w = *(const float4*)&Wl[lane * DIM + ((j4 ^ swr) << 2)];
            #pragma unroll
            for (int k = 0; k < 8; ++k) {
                int tok = tg * 8 + k;
                float4 z = *(const float4*)&zl[tok * DIM + ((j4 ^ (tok & 31)) << 2)];
                acc[k] = fmaf(w.x,z.x,fmaf(w.y,z.y,fmaf(w.z,z.z,fmaf(w.w,z.w,acc[k]))));
            }
        }
        const int pidx = ((row & 127) << 2) + (row >> 7);   // dim*4 + gate
        #pragma unroll
        for (int k = 0; k < 8; ++k) {
            int tok = tg * 8 + k;
            xg[((size_t)(s0 + tok)) * NGATE + pidx] = acc[k];
        }
        __syncthreads();
    }
}

// ---------------------------------------------------------------------------
// K2: MFMA LSTM scan + max-pool. ONE block, 256 threads (4 waves, 1/SIMD).
// ---------------------------------------------------------------------------
__global__ __launch_bounds__(256, 1) void lstm_scan(
    const float* __restrict__ xg, const float* __restrict__ W_hh,
    float* __restrict__ out)
{
    const int T    = threadIdx.x;
    const int wg   = T >> 6;         // wave id: owns dims [32*wg, 32*wg+32)
    const int lane = T & 63;
    const int q    = lane >> 4;      // quad 0..3
    const int c    = lane & 15;      // A row-in-tile; C column
    const int q8   = q * 8;
    // lanes c>=8 mirror c-8 (duplicate identical LDS writes, benign)
    const int d    = wg * 32 + q * 4 + (c & 3) + ((c & 4) ? 16 : 0);

    __shared__ __align__(16) _Float16 hbuf[2][DIM];

    // ---- A-fragments: tile (gate G, half H) rows = G*128 + wg*32 + H*16 + c,
    //      4 K-chunks each; named vars, MFMA-only use -> AGPR-resident ----
#define LOADA(G,H) \
    v8h a##G##H##0, a##G##H##1, a##G##H##2, a##G##H##3; { \
        const float4* p = (const float4*)(W_hh + \
            (size_t)((G) * 128 + wg * 32 + (H) * 16 + c) * DIM) + q * 2; \
        a##G##H##0 = pack8(p[ 0], p[ 1]); \
        a##G##H##1 = pack8(p[ 8], p[ 9]); \
        a##G##H##2 = pack8(p[16], p[17]); \
        a##G##H##3 = pack8(p[24], p[25]); }
    LOADA(0,0) LOADA(0,1) LOADA(1,0) LOADA(1,1)
    LOADA(2,0) LOADA(2,1) LOADA(3,0) LOADA(3,1)
#undef LOADA

    float cst  = 0.0f;
    float hmax = -INFINITY;

    if (T < DIM) hbuf[0][T] = (_Float16)0.0f;   // h_0 = 0
    __syncthreads();   // drains vmcnt(0): HW counter = 0 at this point; all
                       // compiler-tracked loads (W_hh) are complete.

    // per-lane xg column pointer ([t][dim][gate] layout)
    const float* xp = xg + 4 * d;

    // 8 asm loads in flight (rows 0..7). Invariant before step t's wait:
    // outstanding = rows t..t+7; vmcnt(7) completes exactly row t.
    v4f X0, X1, X2, X3, X4, X5, X6, X7;
#define PRELD(n) { const float* _p = xp + (size_t)(n) * NGATE; \
    asm volatile("global_load_dwordx4 %0, %1, off" : "=v"(X##n) : "v"(_p)); }
    PRELD(0) PRELD(1) PRELD(2) PRELD(3) PRELD(4) PRELD(5) PRELD(6) PRELD(7)
#undef PRELD

    const v4f Z4 = {0.0f, 0.0f, 0.0f, 0.0f};

#define MF(G,H,K,B,CIN) __builtin_amdgcn_mfma_f32_16x16x32_f16(a##G##H##K, B, CIN, 0, 0, 0)

#define STEP(XV, tn, bf, nbf) { \
    const v8h B0 = *(const v8h*)&hbuf[bf][ 0 + q8]; \
    const v8h B1 = *(const v8h*)&hbuf[bf][32 + q8]; \
    const v8h B2 = *(const v8h*)&hbuf[bf][64 + q8]; \
    const v8h B3 = *(const v8h*)&hbuf[bf][96 + q8]; \
    asm volatile("s_waitcnt vmcnt(7)" : "+v"(XV));  /* row-t load complete */ \
    const v4f xcur = XV; \
    { const float* _p = xp + (size_t)(tn) * NGATE; \
      asm volatile("global_load_dwordx4 %0, %1, off" : "=v"(XV) : "v"(_p)); } \
    /* K-major: 8 independent MFMAs between accumulator reuses */ \
    v4f c00 = MF(0,0,0,B0,Z4);  v4f c01 = MF(0,1,0,B0,Z4); \
    v4f c10 = MF(1,0,0,B0,Z4);  v4f c11 = MF(1,1,0,B0,Z4); \
    v4f c20 = MF(2,0,0,B0,Z4);  v4f c21 = MF(2,1,0,B0,Z4); \
    v4f c30 = MF(3,0,0,B0,Z4);  v4f c31 = MF(3,1,0,B0,Z4); \
    c00 = MF(0,0,1,B1,c00);  c01 = MF(0,1,1,B1,c01); \
    c10 = MF(1,0,1,B1,c10);  c11 = MF(1,1,1,B1,c11); \
    c20 = MF(2,0,1,B1,c20);  c21 = MF(2,1,1,B1,c21); \
    c30 = MF(3,0,1,B1,c30);  c31 = MF(3,1,1,B1,c31); \
    c00 = MF(0,0,2,B2,c00);  c01 = MF(0,1,2,B2,c01); \
    c10 = MF(1,0,2,B2,c10);  c11 = MF(1,1,2,B2,c11); \
    c20 = MF(2,0,2,B2,c20);  c21 = MF(2,1,2,B2,c21); \
    c30 = MF(3,0,2,B2,c30);  c31 = MF(3,1,2,B2,c31); \
    c00 = MF(0,0,3,B3,c00);  c01 = MF(0,1,3,B3,c01); \
    c10 = MF(1,0,3,B3,c10);  c11 = MF(1,1,3,B3,c11); \
    c20 = MF(2,0,3,B3,c20);  c21 = MF(2,1,3,B3,c21); \
    c30 = MF(3,0,3,B3,c30);  c31 = MF(3,1,3,B3,c31); \
    /* branch-free epilogue on ALL lanes (c>=8 mirrors c-8) */ \
    const float pi = selv(c00, c01, c) + xcur[0]; \
    const float pf = selv(c10, c11, c) + xcur[1]; \
    const float pg = selv(c20, c21, c) + xcur[2]; \
    const float po = selv(c30, c31, c) + xcur[3]; \
    const float iv = sigm_fast(pi); \
    const float fv = sigm_fast(pf); \
    const float gv = tanh_fast(pg); \
    const float ov = sigm_fast(po); \
    cst = fmaf(fv, cst, iv * gv); \
    const float h = ov * tanh_fast(cst); \
    hmax = fmaxf(hmax, h); \
    hbuf[nbf][d] = (_Float16)h; \
    asm volatile("s_waitcnt lgkmcnt(0)\n\ts_barrier" ::: "memory"); }

    for (int t = 0; t < SEQ; t += 8) {
        const int tn0 = (t +  8 < SEQ) ? t +  8 : SEQ - 1;
        const int tn1 = (t +  9 < SEQ) ? t +  9 : SEQ - 1;
        const int tn2 = (t + 10 < SEQ) ? t + 10 : SEQ - 1;
        const int tn3 = (t + 11 < SEQ) ? t + 11 : SEQ - 1;
        const int tn4 = (t + 12 < SEQ) ? t + 12 : SEQ - 1;
        const int tn5 = (t + 13 < SEQ) ? t + 13 : SEQ - 1;
        const int tn6 = (t + 14 < SEQ) ? t + 14 : SEQ - 1;
        const int tn7 = (t + 15 < SEQ) ? t + 15 : SEQ - 1;
        STEP(X0, tn0, 0, 1)
        STEP(X1, tn1, 1, 0)
        STEP(X2, tn2, 0, 1)
        STEP(X3, tn3, 1, 0)
        STEP(X4, tn4, 0, 1)
        STEP(X5, tn5, 1, 0)
        STEP(X6, tn6, 0, 1)
        STEP(X7, tn7, 1, 0)
    }
#undef STEP
#undef MF

    if (c < 8) out[d] = hmax;   // 32 unique dims per wave -> out[1][128]
}

// ---------------------------------------------------------------------------
extern "C" void kernel_launch(void* const* d_in, const int* in_sizes, int n_in,
                              void* d_out, int out_size, void* d_ws, size_t ws_size,
                              hipStream_t stream)
{
    const float* embs  = (const float*)d_in[0];
    const int*   pos   = (const int*)  d_in[1];
    const float* W_exp = (const float*)d_in[2];
    const float* b_exp = (const float*)d_in[3];
    const float* W_ih  = (const float*)d_in[4];
    const float* W_hh  = (const float*)d_in[5];
    const float* b_ih  = (const float*)d_in[6];
    const float* b_hh  = (const float*)d_in[7];
    float* out = (float*)d_out;
    float* xg  = (float*)d_ws;   // [SEQ][512] fp32 = 16 MB

    expert_gemv<<<dim3(NEXP * 8), 64, 0, stream>>>(embs, pos, W_exp, b_exp, xg);
    gate_gemm  <<<dim3(256), 256, 0, stream>>>(W_ih, b_ih, b_hh, xg);
    lstm_scan  <<<dim3(1), 256, 0, stream>>>(xg, W_hh, out);
}